// Round 12
// baseline (37.396 us; speedup 1.0000x reference)
//
#include <hip/hip_runtime.h>

#define C_IN   8
#define CH     8
#define Hh     128
#define Ww     192
#define HW     (Hh*Ww)
#define NINST  128
#define NPAR   169
#define OH     256
#define OW     384
#define B      4             // rows per MLP block (exact, no halo)
#define NRG    (Hh/B)        // 32 row groups

typedef float f32x2 __attribute__((ext_vector_type(2)));
typedef float f32x4 __attribute__((ext_vector_type(4)));

__device__ __forceinline__ f32x2 pk2(float s) { f32x2 r; r.x = s; r.y = s; return r; }

// Packed LDS weight layout (16B-aligned, 192 floats):
//   [0,96): w0 as [8][12] | [96,160): w1 [8][8] | [160,168): w2[8]
//   [168,176): b0 | [176,184): b1 | [184]: b2
//
// Codegen lessons (R6-R11): __launch_bounds__ 2nd arg w caps VGPRs ~256/w
// (w>=4 spills); scalar s_load weights regress (SGPR pressure); monolithic
// pk-paired body is spill-free at w=3. R11 proved VALU issue count is NOT
// the bound -> R12 splits the barrier-locked fused chain into two short
// kernels: MLP -> ws logits; streaming upsample at write-BW.

__global__ __launch_bounds__(192, 3)
void mlp_kernel(const float* __restrict__ feats,
                const float* __restrict__ params,
                const float* __restrict__ locs,
                const int* __restrict__ im_inds,
                const int* __restrict__ fpn,
                float* __restrict__ logits)
{
    __shared__ __align__(16) float sw[192];

    const int rg   = blockIdx.x;    // 0..31
    const int inst = blockIdx.y;    // 0..127
    const int x    = threadIdx.x;   // 0..191 — one column per thread
    const int r0   = rg * B;        // <= 124: rows r0..r0+3 never clamp

    // stage + repack params (coalesced global read, remapped LDS write)
    if (x < NPAR) {
        const int r = x;
        int dst;
        if (r < 80)       { const int o = r / 10; dst = o * 12 + (r - o * 10); }
        else if (r < 144) dst = 96  + (r - 80);
        else if (r < 152) dst = 160 + (r - 144);
        else if (r < 160) dst = 168 + (r - 152);
        else if (r < 168) dst = 176 + (r - 160);
        else              dst = 184;
        sw[dst] = params[inst * NPAR + r];
    }

    const float ixv = locs[inst * 2 + 0];
    const float iyv = locs[inst * 2 + 1];
    const float inv_soi = 1.0f / (float)(64 << fpn[inst]);
    const float rx = (ixv - (float)(x * 8 + 4)) * inv_soi;
    const float* fb = feats + (size_t)im_inds[inst] * (C_IN * HW) + x;

    // rows paired {0,1},{2,3} for v_pk_fma_f32
    f32x2 ry2[2];
    ry2[0].x = (iyv - (float)((r0 + 0) * 8 + 4)) * inv_soi;
    ry2[0].y = (iyv - (float)((r0 + 1) * 8 + 4)) * inv_soi;
    ry2[1].x = (iyv - (float)((r0 + 2) * 8 + 4)) * inv_soi;
    ry2[1].y = (iyv - (float)((r0 + 3) * 8 + 4)) * inv_soi;

    f32x2 f2[2][C_IN];
    #pragma unroll
    for (int c = 0; c < C_IN; ++c) {
        const float* fc = fb + c * HW;
        f2[0][c].x = fc[(r0 + 0) * Ww];
        f2[0][c].y = fc[(r0 + 1) * Ww];
        f2[1][c].x = fc[(r0 + 2) * Ww];
        f2[1][c].y = fc[(r0 + 3) * Ww];
    }

    __syncthreads();

    // ---- layer 1 (10 -> 8)
    f32x2 h1a[CH], h1b[CH];
    #pragma unroll
    for (int o = 0; o < CH; ++o) {
        const f32x4 wa = *(const f32x4*)(sw + o * 12 + 0);
        const f32x4 wb = *(const f32x4*)(sw + o * 12 + 4);
        const f32x4 wc = *(const f32x4*)(sw + o * 12 + 8);   // .z/.w pad
        const float c0 = fmaf(wa.x, rx, sw[168 + o]);        // rx term hoisted
        const float wv[C_IN] = {wa.z, wa.w, wb.x, wb.y, wb.z, wb.w, wc.x, wc.y};

        f32x2 a0 = pk2(wa.y) * ry2[0] + pk2(c0);
        f32x2 a1 = pk2(wa.y) * ry2[1] + pk2(c0);
        #pragma unroll
        for (int c = 0; c < C_IN; ++c) {
            a0 = pk2(wv[c]) * f2[0][c] + a0;
            a1 = pk2(wv[c]) * f2[1][c] + a1;
        }
        h1a[o].x = fmaxf(a0.x, 0.0f);  h1a[o].y = fmaxf(a0.y, 0.0f);
        h1b[o].x = fmaxf(a1.x, 0.0f);  h1b[o].y = fmaxf(a1.y, 0.0f);
    }

    // ---- layer 2 (8 -> 8)
    f32x2 h2a[CH], h2b[CH];
    #pragma unroll
    for (int o = 0; o < CH; ++o) {
        const f32x4 wa = *(const f32x4*)(sw + 96 + o * 8 + 0);
        const f32x4 wb = *(const f32x4*)(sw + 96 + o * 8 + 4);
        const float bo = sw[176 + o];
        const float wv[CH] = {wa.x, wa.y, wa.z, wa.w, wb.x, wb.y, wb.z, wb.w};

        f32x2 a0 = pk2(bo);
        f32x2 a1 = pk2(bo);
        #pragma unroll
        for (int c = 0; c < CH; ++c) {
            a0 = pk2(wv[c]) * h1a[c] + a0;
            a1 = pk2(wv[c]) * h1b[c] + a1;
        }
        h2a[o].x = fmaxf(a0.x, 0.0f);  h2a[o].y = fmaxf(a0.y, 0.0f);
        h2b[o].x = fmaxf(a1.x, 0.0f);  h2b[o].y = fmaxf(a1.y, 0.0f);
    }

    // ---- layer 3 (8 -> 1) -> global logits
    {
        const f32x4 wa = *(const f32x4*)(sw + 160);
        const f32x4 wb = *(const f32x4*)(sw + 164);
        const float bo = sw[184];
        const float wv[CH] = {wa.x, wa.y, wa.z, wa.w, wb.x, wb.y, wb.z, wb.w};

        f32x2 z0 = pk2(bo);
        f32x2 z1 = pk2(bo);
        #pragma unroll
        for (int c = 0; c < CH; ++c) {
            z0 = pk2(wv[c]) * h2a[c] + z0;
            z1 = pk2(wv[c]) * h2b[c] + z1;
        }
        float* lp = logits + ((size_t)inst * Hh + r0) * Ww + x;
        lp[0 * Ww] = z0.x;
        lp[1 * Ww] = z0.y;
        lp[2 * Ww] = z1.x;
        lp[3 * Ww] = z1.y;
    }
}

// out[oy][ox]: ay=max(oy-1,0), y0=ay>>1, y1=min(y0+1,127), fy=(ay&1)?0.5:0
// rm(m) = logits row-mix at source col clamp(m,0); out[2m]=0.5*(rm(m-1)+rm(m)),
// out[2m+1]=rm(m). One thread per output float4 (cols 4g..4g+3).
__global__ __launch_bounds__(256)
void upsample_kernel(const float* __restrict__ logits, f32x4* __restrict__ out)
{
    const int idx  = blockIdx.x * 256 + threadIdx.x;   // float4 index
    const int g    = idx % (OW / 4);
    const int r    = idx / (OW / 4);
    const int oy   = r % OH;
    const int inst = r / OH;

    const float* L = logits + (size_t)inst * HW;

    const int ay = max(oy - 1, 0);
    const int y0 = ay >> 1;
    const int y1 = min(y0 + 1, Hh - 1);
    const float fy = (ay & 1) ? 0.5f : 0.0f;

    const int m0  = 2 * g;
    const int mm1 = max(m0 - 1, 0);
    const int mp1 = m0 + 1;                            // <= 191

    const float* La = L + y0 * Ww;
    const float* Lb = L + y1 * Ww;
    const float a0 = La[mm1], a1 = La[m0], a2 = La[mp1];
    const float b0 = Lb[mm1], b1 = Lb[m0], b2 = Lb[mp1];

    const float r0v = fmaf(fy, b0 - a0, a0);           // rm(m-1)
    const float r1v = fmaf(fy, b1 - a1, a1);           // rm(m)
    const float r2v = fmaf(fy, b2 - a2, a2);           // rm(m+1)

    f32x4 v;
    v.x = 0.5f * (r0v + r1v);
    v.y = r1v;
    v.z = 0.5f * (r1v + r2v);
    v.w = r2v;
    out[idx] = v;
}

extern "C" void kernel_launch(void* const* d_in, const int* in_sizes, int n_in,
                              void* d_out, int out_size, void* d_ws, size_t ws_size,
                              hipStream_t stream) {
    const float* feats  = (const float*)d_in[0];
    const float* params = (const float*)d_in[1];
    const float* locs   = (const float*)d_in[2];
    const int*   im     = (const int*)d_in[3];
    const int*   fpn    = (const int*)d_in[4];
    float* out    = (float*)d_out;
    float* logits = (float*)d_ws;   // 128*128*192*4 = 12.58 MB

    dim3 g1(NRG, NINST);   // 32 x 128 = 4096 blocks
    mlp_kernel<<<g1, 192, 0, stream>>>(feats, params, locs, im, fpn, logits);

    const int nf4 = NINST * OH * (OW / 4);   // 3,145,728
    upsample_kernel<<<nf4 / 256, 256, 0, stream>>>(logits, (f32x4*)out);
}